// Round 11
// baseline (147.971 us; speedup 1.0000x reference)
//
#include <hip/hip_runtime.h>

// LlamaAttention — Round 18: ZERO-workspace single-kernel fused two-GEMM.
//
// out = (x @ Wv^T) @ Wo^T  (softmax == I, established r0-r17).
// r17 post-mortem: 3rd consecutive null on kernel-internal scheduling; the
// headline's missing ~75us is visible in the counters: the harness
// re-poisons the 256 MiB workspace with fillBufferAligned (~42-44us per
// fill) every iteration BECAUSE we use d_ws, plus ~12us prep dispatch.
// r18 removes the workspace entirely: V = x@Wv^T is ROW-LOCAL per block,
// so both GEMMs fuse into one kernel with V in LDS. Wv/Wo (768 KB each)
// stream f32 from L2 with cvt->f16 at consume; x-stage and K-loop
// rotation are the r12-proven patterns. One dispatch, d_ws untouched.
// Numerics: f16 operands, fp32 accum, V->f16 (adds ~1e-4); predicted
// absmax ~0.004-0.006 (r7's bf16 two-GEMM passed at 0.0049).

typedef unsigned short u16;
typedef __attribute__((ext_vector_type(8))) short short8;      // 16 B
typedef __attribute__((ext_vector_type(8))) _Float16 f16x8;    // 4 VGPR MFMA frag
typedef __attribute__((ext_vector_type(4))) float float4v;

__device__ inline u16 f16b(float f) {
  union { _Float16 h; u16 u; } v; v.h = (_Float16)f; return v.u;  // v_cvt_f16_f32 RNE
}

__device__ inline f16x8 cv8(float4v a, float4v b) {   // 8x f32 -> f16x8 (RNE)
  f16x8 r;
#pragma unroll
  for (int e = 0; e < 4; ++e) { r[e] = (_Float16)a[e]; r[e + 4] = (_Float16)b[e]; }
  return r;
}

// ---------------- the whole op in one kernel, no workspace ----------------
// Block: 512 thr / 8 waves; rows row0..row0+63.
// GEMM1: wave w -> V cols w*32..+31 (jn=0,1).  GEMM2: wave w -> out cols
// w*96..+95 (jn=0..5).  LDS: S = x stripe f16 [64][96 chunks, c^(row&7)],
// VL = V f16 [64][32 chunks, c^(row&7)].  131 KB -> 1 block/CU.
__global__ __launch_bounds__(512, 2)
void fused2(const float* __restrict__ x, const float* __restrict__ Wv,
            const float* __restrict__ Wo, float* __restrict__ out) {
  __shared__ __align__(16) u16 S[64 * 768];     // 96 KB
  __shared__ __align__(16) u16 VL[64 * 256];    // 32 KB

  const int tid = threadIdx.x;
  const int w = tid >> 6, l = tid & 63;
  const int q = l >> 4, mr = l & 15;
  const int row0 = blockIdx.x * 64;
  const int akey = mr & 7;

  // ---- stage x[64][768] fp32 -> LDS f16, chunk-swizzled (r12-proven) ----
  {
    const int sr = ((w & 3) << 4) + mr;           // row 0..63
    const int half = w >> 2;                      // even/odd chunk quads
    const float* gr = x + (size_t)(row0 + sr) * 768;
    u16* lr = S + sr * 768;
    const int key = sr & 7;
#pragma unroll
    for (int j = 0; j < 12; ++j) {
      const int c = q + 4 * (2 * j + half);       // chunk 0..95
      float4v v0 = *(const float4v*)(gr + c * 8);
      float4v v1 = *(const float4v*)(gr + c * 8 + 4);
      union { u16 h[8]; short8 s; } p;
#pragma unroll
      for (int e = 0; e < 4; ++e) { p.h[e] = f16b(v0[e]); p.h[e + 4] = f16b(v1[e]); }
      *(short8*)(lr + ((c ^ key) << 3)) = p.s;
    }
  }
  __syncthreads();

  // ============ GEMM1: V[64][256] = x @ Wv^T (K = 768, 24 tiles) ============
  {
    float4v acc1[4][2];
#pragma unroll
    for (int i = 0; i < 4; ++i)
#pragma unroll
      for (int j = 0; j < 2; ++j) acc1[i][j] = (float4v){0.f, 0.f, 0.f, 0.f};

    f16x8 a0[4], a1[4];
    float4v e0a, e0b, e1a, e1b, o0a, o0b, o1a, o1b;   // B f32, 2 frags x 2 deep

#define LDA1(av_, kt_)                                                       \
    _Pragma("unroll")                                                        \
    for (int im = 0; im < 4; ++im)                                           \
      av_[im] = *(const f16x8*)(                                             \
          &S[(im * 16 + mr) * 768 + ((((kt_) * 4 + q) ^ akey) << 3)]);

// Two B-frag cols per wave: (w*32+mr) and (w*32+16+mr); 8 f32 each.
#define LDB1(s0a_, s0b_, s1a_, s1b_, kt_)                                    \
    { const float* p0 = Wv + (size_t)(w * 32 + mr) * 768 + (kt_) * 32 + q * 8; \
      const float* p1 = p0 + 16 * 768;                                       \
      s0a_ = *(const float4v*)p0; s0b_ = *(const float4v*)(p0 + 4);          \
      s1a_ = *(const float4v*)p1; s1b_ = *(const float4v*)(p1 + 4); }

#define MM1(av_, s0a_, s0b_, s1a_, s1b_)                                     \
    { f16x8 bf0 = cv8(s0a_, s0b_), bf1 = cv8(s1a_, s1b_);                    \
      __builtin_amdgcn_s_setprio(1);                                         \
      _Pragma("unroll")                                                      \
      for (int im = 0; im < 4; ++im) {                                       \
        acc1[im][0] = __builtin_amdgcn_mfma_f32_16x16x32_f16(av_[im], bf0, acc1[im][0], 0, 0, 0); \
        acc1[im][1] = __builtin_amdgcn_mfma_f32_16x16x32_f16(av_[im], bf1, acc1[im][1], 0, 0, 0); \
      }                                                                      \
      __builtin_amdgcn_s_setprio(0); }

    LDB1(e0a, e0b, e1a, e1b, 0)
    LDA1(a0, 0)
    for (int kt = 0; kt < 22; kt += 2) {
      LDB1(o0a, o0b, o1a, o1b, kt + 1) LDA1(a1, kt + 1)
      MM1(a0, e0a, e0b, e1a, e1b)
      LDB1(e0a, e0b, e1a, e1b, kt + 2) LDA1(a0, kt + 2)
      MM1(a1, o0a, o0b, o1a, o1b)
    }
    LDB1(o0a, o0b, o1a, o1b, 23) LDA1(a1, 23)
    MM1(a0, e0a, e0b, e1a, e1b)
    MM1(a1, o0a, o0b, o1a, o1b)

#undef LDA1
#undef LDB1
#undef MM1

    // ---- V -> LDS f16, swizzled (C/D: col=lane&15, row=q*4+reg) ----
#pragma unroll
    for (int im = 0; im < 4; ++im)
#pragma unroll
      for (int jn = 0; jn < 2; ++jn) {
        const int col = w * 32 + jn * 16 + mr;
        const int cc = col >> 3, ce = col & 7;
#pragma unroll
        for (int r = 0; r < 4; ++r) {
          const int rr = im * 16 + q * 4 + r;
          VL[rr * 256 + ((cc ^ (rr & 7)) << 3) + ce] = f16b(acc1[im][jn][r]);
        }
      }
  }
  __syncthreads();

  // ============ GEMM2: out[64][768] = V @ Wo^T (K = 256, 8 tiles) ===========
  float4v acc2[4][6];
#pragma unroll
  for (int i = 0; i < 4; ++i)
#pragma unroll
    for (int j = 0; j < 6; ++j) acc2[i][j] = (float4v){0.f, 0.f, 0.f, 0.f};

  {
    f16x8 c0[4], c1[4];
    float4v ge[6][2], go[6][2];                    // B f32, 6 frags x 2 deep

#define LDA2(av_, kt_)                                                       \
    _Pragma("unroll")                                                        \
    for (int im = 0; im < 4; ++im)                                           \
      av_[im] = *(const f16x8*)(                                             \
          &VL[(im * 16 + mr) * 256 + ((((kt_) * 4 + q) ^ akey) << 3)]);

#define LDB2(bv_, kt_)                                                       \
    _Pragma("unroll")                                                        \
    for (int jn = 0; jn < 6; ++jn) {                                         \
      const float* p = Wo + (size_t)(w * 96 + jn * 16 + mr) * 256 + (kt_) * 32 + q * 8; \
      bv_[jn][0] = *(const float4v*)p;                                       \
      bv_[jn][1] = *(const float4v*)(p + 4);                                 \
    }

#define MM2(av_, bv_)                                                        \
    { __builtin_amdgcn_s_setprio(1);                                         \
      _Pragma("unroll")                                                      \
      for (int jn = 0; jn < 6; ++jn) {                                       \
        f16x8 bf = cv8(bv_[jn][0], bv_[jn][1]);                              \
        _Pragma("unroll")                                                    \
        for (int im = 0; im < 4; ++im)                                       \
          acc2[im][jn] = __builtin_amdgcn_mfma_f32_16x16x32_f16(av_[im], bf, acc2[im][jn], 0, 0, 0); \
      }                                                                      \
      __builtin_amdgcn_s_setprio(0); }

    LDB2(ge, 0)
    LDA2(c0, 0)
    for (int kt = 0; kt < 6; kt += 2) {
      LDB2(go, kt + 1) LDA2(c1, kt + 1)
      MM2(c0, ge)
      LDB2(ge, kt + 2) LDA2(c0, kt + 2)
      MM2(c1, go)
    }
    LDB2(go, 7) LDA2(c1, 7)
    MM2(c0, ge)
    MM2(c1, go)

#undef LDA2
#undef LDB2
#undef MM2
  }

  // ---- epilogue: C/D col=lane&15, row=q*4+reg (m89-verified) ----
#pragma unroll
  for (int im = 0; im < 4; ++im)
#pragma unroll
    for (int jn = 0; jn < 6; ++jn) {
      const int r0 = row0 + im * 16 + q * 4;
      const int c  = w * 96 + jn * 16 + mr;
#pragma unroll
      for (int r = 0; r < 4; ++r)
        out[(size_t)(r0 + r) * 768 + c] = acc2[im][jn][r];
    }
}

extern "C" void kernel_launch(void* const* d_in, const int* in_sizes, int n_in,
                              void* d_out, int out_size, void* d_ws, size_t ws_size,
                              hipStream_t stream) {
  (void)in_sizes; (void)n_in; (void)out_size;
  (void)d_ws; (void)ws_size;                 // workspace deliberately UNUSED
  const float* x  = (const float*)d_in[0];   // [16384, 768]
  const float* Wv = (const float*)d_in[3];   // [256, 768]
  const float* Wo = (const float*)d_in[4];   // [768, 256]
  float* out = (float*)d_out;

  fused2<<<dim3(256), dim3(512), 0, stream>>>(x, Wv, Wo, out);
}

// Round 12
// 131.854 us; speedup vs baseline: 1.1222x; 1.1222x over previous
//
#include <hip/hip_runtime.h>

// LlamaAttention — Round 19: r16 + per-block staggered K order (L2 de-hotspot).
//
// out = x @ (Wo @ Wv)^T  (softmax == I, established r0-r18).
// r18 closed the headline accounting: ~84us = two UNCONDITIONAL 256MiB
// workspace poison-fills (persist with d_ws unused) + gemm ~42 + prep ~4.
// Only lever: the GEMM. Remaining theory for 42 vs ~26 phase-sum: all 256
// blocks stream W in near-lockstep -> all 32 CUs/XCD hit the SAME W-tile
// L2 lines simultaneously (same-line hotspot throttles the 4.3 TB/s/XCD
// stream to ~2). Fix: block b processes K-tiles in order s, s+1, ..
// (mod 24), s = b%24 -> requests spread uniformly over W. fp32 accum
// order changes by ~1e-6 (passing absmax 0.0039). Else r16 verbatim.

typedef unsigned short u16;
typedef __attribute__((ext_vector_type(8))) short short8;      // 16 B
typedef __attribute__((ext_vector_type(8))) _Float16 f16x8;    // 4 VGPR MFMA frag
typedef __attribute__((ext_vector_type(4))) float float4v;

__device__ inline u16 f16b(float f) {
  union { _Float16 h; u16 u; } v; v.h = (_Float16)f; return v.u;  // v_cvt_f16_f32 RNE
}

__device__ inline u16 f32_to_bf16(float f) {        // fallback path only
  union { float f; unsigned int u; } v; v.f = f;
  unsigned int r = v.u + 0x7FFF + ((v.u >> 16) & 1);
  return (u16)(r >> 16);
}

// ---------------- prep: W = Wo @ Wv, fp32 accum, f16 tiled ----------------
// wt layout: element (o, h) at wt[(h>>5)*24576 + o*32 + ((h>>3)&3)*8 + (h&7)]
// (wave frag load = 1 KB contiguous). Bit-identical W vs r10-r18.
__global__ __launch_bounds__(256)
void prep_w(const float* __restrict__ Wv, const float* __restrict__ Wo,
            u16* __restrict__ wt) {
  __shared__ __align__(16) float wo[4][256];            // 4 KB
  const int og = blockIdx.x / 3, hc = blockIdx.x % 3;   // 192 o-grp x 3 h-chunk
  const int o0 = og * 4;
  ((float4v*)&wo[0][0])[threadIdx.x] =
      ((const float4v*)(Wo + (size_t)o0 * 256))[threadIdx.x];
  __syncthreads();
  const int h = hc * 256 + threadIdx.x;
  float acc[4] = {0.f, 0.f, 0.f, 0.f};
  float wvA[8], wvB[8];
#pragma unroll
  for (int u = 0; u < 8; ++u) wvA[u] = Wv[(size_t)u * 768 + h];

#define PFMA(wv_, kk_)                                                       \
  _Pragma("unroll")                                                          \
  for (int j = 0; j < 4; ++j) {                                              \
    float4v c0 = *(const float4v*)(&wo[j][kk_]);                             \
    float4v c1 = *(const float4v*)(&wo[j][(kk_) + 4]);                       \
    acc[j] = fmaf(c0[0], wv_[0], acc[j]);                                    \
    acc[j] = fmaf(c0[1], wv_[1], acc[j]);                                    \
    acc[j] = fmaf(c0[2], wv_[2], acc[j]);                                    \
    acc[j] = fmaf(c0[3], wv_[3], acc[j]);                                    \
    acc[j] = fmaf(c1[0], wv_[4], acc[j]);                                    \
    acc[j] = fmaf(c1[1], wv_[5], acc[j]);                                    \
    acc[j] = fmaf(c1[2], wv_[6], acc[j]);                                    \
    acc[j] = fmaf(c1[3], wv_[7], acc[j]);                                    \
  }

  for (int k = 0; k < 240; k += 16) {
#pragma unroll
    for (int u = 0; u < 8; ++u) wvB[u] = Wv[(size_t)(k + 8 + u) * 768 + h];
    PFMA(wvA, k)
#pragma unroll
    for (int u = 0; u < 8; ++u) wvA[u] = Wv[(size_t)(k + 16 + u) * 768 + h];
    PFMA(wvB, k + 8)
  }
#pragma unroll
  for (int u = 0; u < 8; ++u) wvB[u] = Wv[(size_t)(248 + u) * 768 + h];
  PFMA(wvA, 240)
  PFMA(wvB, 248)
#undef PFMA

  const int kt = h >> 5, qq = (h >> 3) & 3, e = h & 7;
#pragma unroll
  for (int j = 0; j < 4; ++j)
    wt[(size_t)kt * 24576 + (o0 + j) * 32 + qq * 8 + e] = f16b(acc[j]);
}

// ---------------- main: out[16384,768] = x @ W^T, staggered K order -------
// Block: 512 thr / 8 waves; 64 rows x 768 cols; wave w owns cols w*96..+95
// (disjoint -> W read once per block). LDS: x stripe f16 [64][96 chunks],
// chunk stored at c^(row&7) (A-frag reads 2-way max = free).
__global__ __launch_bounds__(512, 2)
void gemm_xw(const float* __restrict__ x, const u16* __restrict__ wt,
             float* __restrict__ out) {
  __shared__ __align__(16) u16 S[64 * 768];       // 96 KB -> 1 block/CU

  const int tid = threadIdx.x;
  const int w = tid >> 6, l = tid & 63;
  const int q = l >> 4, mr = l & 15;
  const int row0 = blockIdx.x * 64;

  // B-frag lane base: wt + col*32 + q*8, col = w*96 + jn*16 + mr
  const u16* wl = wt + (w * 96 + mr) * 32 + q * 8;
  const int akey = mr & 7;

  f16x8 a0[4], a1[4], a2[4], b0[6], b1[6], b2[6];

// One 16B global load, asm-pinned (compiler cannot sink/serialize it).
#define GLD_OFF(dst_, base_, OFFSTR)                                         \
  asm volatile("global_load_dwordx4 %0, %1, off offset:" OFFSTR              \
               : "=v"(dst_) : "v"(base_) : "memory");

// jn stride = 512 u16 = 1024 B; offsets must stay < 4096 -> two bases.
#define LDB_ASM(bv_, kt_)                                                    \
  { const u16* gbase  = wl + (size_t)(kt_) * 24576;                          \
    const u16* gbase2 = gbase + 2048;                                        \
    GLD_OFF(bv_[0], gbase,  "0")                                             \
    GLD_OFF(bv_[1], gbase,  "1024")                                          \
    GLD_OFF(bv_[2], gbase,  "2048")                                          \
    GLD_OFF(bv_[3], gbase,  "3072")                                          \
    GLD_OFF(bv_[4], gbase2, "0")                                             \
    GLD_OFF(bv_[5], gbase2, "1024") }

#define LDA(av_, kt_)                                                        \
  _Pragma("unroll")                                                          \
  for (int im = 0; im < 4; ++im)                                             \
    av_[im] = *(const f16x8*)(                                               \
        &S[(im * 16 + mr) * 768 + ((((kt_) * 4 + q) ^ akey) << 3)]);

// Counted wait + scheduling fence (rule #18: MFMA hoists past asm waitcnt
// without sched_barrier).
#define WAITB(NSTR)                                                          \
  asm volatile("s_waitcnt vmcnt(" NSTR ")" ::: "memory");                    \
  __builtin_amdgcn_sched_barrier(0);

#define MM(av_, bv_)                                                         \
  { __builtin_amdgcn_s_setprio(1);                                           \
    _Pragma("unroll")                                                        \
    for (int im = 0; im < 4; ++im)                                           \
      _Pragma("unroll")                                                      \
      for (int jn = 0; jn < 6; ++jn)                                         \
        acc[im][jn] = __builtin_amdgcn_mfma_f32_16x16x32_f16(                \
            av_[im], bv_[jn], acc[im][jn], 0, 0, 0);                         \
    __builtin_amdgcn_s_setprio(0); }

// Wrap-increment for staggered tile index (0..23).
#define ADV(k_) k_ = ((k_) == 23) ? 0 : ((k_) + 1);

  // ---- staggered start: block b begins at tile s = b % 24 ----
  const int s0 = blockIdx.x % 24;
  int i1 = (s0 == 23) ? 0 : s0 + 1;
  int i2 = (i1 == 23) ? 0 : i1 + 1;

  // ---- prologue: 18 asm B loads in flight, then stage under them ----
  LDB_ASM(b0, s0)
  LDB_ASM(b1, i1)
  LDB_ASM(b2, i2)

  // stage x[64][768] fp32 -> LDS f16, chunk-swizzled (r12-measured code)
  {
    const int sr = ((w & 3) << 4) + mr;           // row 0..63
    const int half = w >> 2;                      // even/odd chunk quads
    const float* gr = x + (size_t)(row0 + sr) * 768;
    u16* lr = S + sr * 768;
    const int key = sr & 7;
#pragma unroll
    for (int j = 0; j < 12; ++j) {
      const int c = q + 4 * (2 * j + half);       // chunk 0..95
      float4v v0 = *(const float4v*)(gr + c * 8);
      float4v v1 = *(const float4v*)(gr + c * 8 + 4);
      union { u16 h[8]; short8 s; } p;
#pragma unroll
      for (int e = 0; e < 4; ++e) { p.h[e] = f16b(v0[e]); p.h[e + 4] = f16b(v1[e]); }
      *(short8*)(lr + ((c ^ key) << 3)) = p.s;
    }
  }
  // Raw barrier: drain only LDS writes; B loads STAY in flight.
  asm volatile("s_waitcnt lgkmcnt(0)" ::: "memory");
  __builtin_amdgcn_s_barrier();

  float4v acc[4][6];
#pragma unroll
  for (int i = 0; i < 4; ++i)
#pragma unroll
    for (int j = 0; j < 6; ++j) acc[i][j] = (float4v){0.f, 0.f, 0.f, 0.f};

  LDA(a0, s0)
  LDA(a1, i1)
  LDA(a2, i2)

  int kn = (i2 == 23) ? 0 : i2 + 1;              // next tile to fetch

  // ---- steady: uniform body, 2 B-tiles always in flight ----
  // Invariant at each WAITB(12): 18 B loads outstanding; retires oldest 6.
  for (int p = 0; p < 7; ++p) {
    WAITB("12") MM(a0, b0) LDB_ASM(b0, kn) LDA(a0, kn) ADV(kn)
    WAITB("12") MM(a1, b1) LDB_ASM(b1, kn) LDA(a1, kn) ADV(kn)
    WAITB("12") MM(a2, b2) LDB_ASM(b2, kn) LDA(a2, kn) ADV(kn)
  }
  // tail: the last three tiles are already issued and a-sets loaded
  WAITB("12") MM(a0, b0)
  WAITB("6")  MM(a1, b1)
  WAITB("0")  MM(a2, b2)

#undef GLD_OFF
#undef LDB_ASM
#undef LDA
#undef WAITB
#undef MM
#undef ADV

  // ---- epilogue: C/D col=lane&15, row=q*4+reg (m89-verified) ----
#pragma unroll
  for (int im = 0; im < 4; ++im)
#pragma unroll
    for (int jn = 0; jn < 6; ++jn) {
      const int r0 = row0 + im * 16 + q * 4;
      const int c  = w * 96 + jn * 16 + mr;
#pragma unroll
      for (int r = 0; r < 4; ++r)
        out[(size_t)(r0 + r) * 768 + c] = acc[im][jn][r];
    }
}

// ---------------- fallback (no workspace): verified r7 kernel ----------------
__global__ __launch_bounds__(512, 1)
void fused_fallback(const float* __restrict__ x,
                    const float* __restrict__ Wv, const float* __restrict__ Wo,
                    float* __restrict__ out) {
  __shared__ __align__(16) u16 As[64 * 32];
  __shared__ __align__(16) u16 Bs[256 * 32];
  __shared__ __align__(16) u16 Vs[64 * 264];

  const int tid = threadIdx.x;
  const int w  = tid >> 6, l = tid & 63;
  const int q  = l >> 4, mr = l & 15;
  const int wm = w & 1, wn = w >> 1;
  const int row0 = blockIdx.x * 64;
  const int xr = tid >> 3, xg = (tid & 7) * 4;
  const int wr = tid >> 1, wh = (tid & 1) * 16;

  float4v acc[2][4];
#pragma unroll
  for (int i = 0; i < 2; ++i)
#pragma unroll
    for (int j = 0; j < 4; ++j) acc[i][j] = (float4v){0.f, 0.f, 0.f, 0.f};

  for (int kt = 0; kt < 24; ++kt) {
    const int k0 = kt * 32;
    {
      float4v v = *(const float4v*)(x + (size_t)(row0 + xr) * 768 + k0 + xg);
      union { u16 h[4]; uint2 u; } p;
      p.h[0] = f32_to_bf16(v[0]); p.h[1] = f32_to_bf16(v[1]);
      p.h[2] = f32_to_bf16(v[2]); p.h[3] = f32_to_bf16(v[3]);
      *(uint2*)(As + xr * 32 + xg) = p.u;
    }
    {
      const float* g = Wv + (size_t)wr * 768 + k0 + wh;
      union { u16 h[16]; short8 s[2]; } p;
#pragma unroll
      for (int u = 0; u < 4; ++u) {
        float4v v = *(const float4v*)(g + u * 4);
        p.h[u * 4 + 0] = f32_to_bf16(v[0]); p.h[u * 4 + 1] = f32_to_bf16(v[1]);
        p.h[u * 4 + 2] = f32_to_bf16(v[2]); p.h[u * 4 + 3] = f32_to_bf16(v[3]);
      }
      *(short8*)(Bs + wr * 32 + wh) = p.s[0];
      *(short8*)(Bs + wr * 32 + wh + 8) = p.s[1];
    }
    __syncthreads();

    short8 a[2], b[4];
#pragma unroll
    for (int i = 0; i < 2; ++i)
      a[i] = *(const short8*)(As + (wm * 32 + i * 16 + mr) * 32 + q * 8);
#pragma unroll
    for (int j = 0; j < 4; ++j)
      b[j] = *(const short8*)(Bs + (wn * 64 + j * 16 + mr) * 32 + q * 8);
#pragma unroll
    for (int i = 0; i < 2; ++i)
#pragma unroll
      for (int j = 0; j < 4; ++j)
        acc[i][j] = __builtin_amdgcn_mfma_f32_16x16x32_bf16(a[i], b[j], acc[i][j], 0, 0, 0);
    __syncthreads();
  }

#pragma unroll
  for (int i = 0; i < 2; ++i)
#pragma unroll
    for (int j = 0; j < 4; ++j) {
      int row = wm * 32 + i * 16 + q * 4;
      int col = wn * 64 + j * 16 + mr;
#pragma unroll
      for (int r = 0; r < 4; ++r)
        Vs[(row + r) * 264 + col] = f32_to_bf16(acc[i][j][r]);
    }
  __syncthreads();

  for (int c = 0; c < 3; ++c) {
    float4v acc2[2][4];
#pragma unroll
    for (int i = 0; i < 2; ++i)
#pragma unroll
      for (int j = 0; j < 4; ++j) acc2[i][j] = (float4v){0.f, 0.f, 0.f, 0.f};

    for (int kt = 0; kt < 8; ++kt) {
      const int k0 = kt * 32;
      {
        const float* g = Wo + (size_t)(c * 256 + wr) * 256 + k0 + wh;
        union { u16 h[16]; short8 s[2]; } p;
#pragma unroll
        for (int u = 0; u < 4; ++u) {
          float4v v = *(const float4v*)(g + u * 4);
          p.h[u * 4 + 0] = f32_to_bf16(v[0]); p.h[u * 4 + 1] = f32_to_bf16(v[1]);
          p.h[u * 4 + 2] = f32_to_bf16(v[2]); p.h[u * 4 + 3] = f32_to_bf16(v[3]);
        }
        *(short8*)(Bs + wr * 32 + wh) = p.s[0];
        *(short8*)(Bs + wr * 32 + wh + 8) = p.s[1];
      }
      __syncthreads();

      short8 a[2], b[4];
#pragma unroll
      for (int i = 0; i < 2; ++i)
        a[i] = *(const short8*)(Vs + (wm * 32 + i * 16 + mr) * 264 + k0 + q * 8);
#pragma unroll
      for (int j = 0; j < 4; ++j)
        b[j] = *(const short8*)(Bs + (wn * 64 + j * 16 + mr) * 32 + q * 8);
#pragma unroll
      for (int i = 0; i < 2; ++i)
#pragma unroll
        for (int j = 0; j < 4; ++j)
          acc2[i][j] = __builtin_amdgcn_mfma_f32_16x16x32_bf16(a[i], b[j], acc2[i][j], 0, 0, 0);
      __syncthreads();
    }

#pragma unroll
    for (int i = 0; i < 2; ++i)
#pragma unroll
      for (int j = 0; j < 4; ++j) {
        int row = row0 + wm * 32 + i * 16 + q * 4;
        int col = c * 256 + wn * 64 + j * 16 + mr;
#pragma unroll
        for (int r = 0; r < 4; ++r)
          out[(size_t)(row + r) * 768 + col] = acc2[i][j][r];
      }
  }
}

extern "C" void kernel_launch(void* const* d_in, const int* in_sizes, int n_in,
                              void* d_out, int out_size, void* d_ws, size_t ws_size,
                              hipStream_t stream) {
  (void)in_sizes; (void)n_in; (void)out_size;
  const float* x  = (const float*)d_in[0];  // [16384, 768]
  const float* Wv = (const float*)d_in[3];  // [256, 768]
  const float* Wo = (const float*)d_in[4];  // [768, 256]
  float* out = (float*)d_out;

  if (ws_size >= (size_t)768 * 768 * 2) {   // 1.18 MB f16 combined weight
    u16* wt = (u16*)d_ws;
    prep_w<<<dim3(576), dim3(256), 0, stream>>>(Wv, Wo, wt);
    gemm_xw<<<dim3(256), dim3(512), 0, stream>>>(x, wt, out);
  } else {
    fused_fallback<<<dim3(256), dim3(512), 0, stream>>>(x, Wv, Wo, out);
  }
}

// Round 13
// 128.964 us; speedup vs baseline: 1.1474x; 1.0224x over previous
//
#include <hip/hip_runtime.h>

// LlamaAttention — Round 20: 16-wave TLP variant (same economics as r12).
//
// out = x @ (Wo @ Wv)^T  (softmax == I, established r0-r19).
// r19 post-mortem: 4th scheduling null; gemm defends ~42us vs six
// instruction-order attacks. The never-isolated axis is TLP: all kernels
// since r12 run 2 waves/SIMD (512thr, 1 blk/CU) — minimum latency hiding.
// r20 keeps EVERY proven economic property (1 blk/CU, 64-row stripe,
// W read once/block, 96KB LDS, L2-direct B stream, 2-deep rotation) and
// only raises waves/SIMD 2 -> 4 via a 1024-thread block: 16 waves x
// 48 cols each (acc 4x3=48 VGPR; budget ~119 <= 128 @ launch_bounds(1024,4)).
// Pre-commit: ~31-35us => TLP was the gap; ~42us => structural plateau.

typedef unsigned short u16;
typedef __attribute__((ext_vector_type(8))) short short8;      // 16 B
typedef __attribute__((ext_vector_type(8))) _Float16 f16x8;    // 4 VGPR MFMA frag
typedef __attribute__((ext_vector_type(4))) float float4v;

__device__ inline u16 f16b(float f) {
  union { _Float16 h; u16 u; } v; v.h = (_Float16)f; return v.u;  // v_cvt_f16_f32 RNE
}

__device__ inline u16 f32_to_bf16(float f) {        // fallback path only
  union { float f; unsigned int u; } v; v.f = f;
  unsigned int r = v.u + 0x7FFF + ((v.u >> 16) & 1);
  return (u16)(r >> 16);
}

// ---------------- prep: W = Wo @ Wv, fp32 accum, f16 tiled ----------------
// wt layout: element (o, h) at wt[(h>>5)*24576 + o*32 + ((h>>3)&3)*8 + (h&7)]
// (wave frag load = contiguous). Bit-identical W vs r10-r19.
__global__ __launch_bounds__(256)
void prep_w(const float* __restrict__ Wv, const float* __restrict__ Wo,
            u16* __restrict__ wt) {
  __shared__ __align__(16) float wo[4][256];            // 4 KB
  const int og = blockIdx.x / 3, hc = blockIdx.x % 3;   // 192 o-grp x 3 h-chunk
  const int o0 = og * 4;
  ((float4v*)&wo[0][0])[threadIdx.x] =
      ((const float4v*)(Wo + (size_t)o0 * 256))[threadIdx.x];
  __syncthreads();
  const int h = hc * 256 + threadIdx.x;
  float acc[4] = {0.f, 0.f, 0.f, 0.f};
  float wvA[8], wvB[8];
#pragma unroll
  for (int u = 0; u < 8; ++u) wvA[u] = Wv[(size_t)u * 768 + h];

#define PFMA(wv_, kk_)                                                       \
  _Pragma("unroll")                                                          \
  for (int j = 0; j < 4; ++j) {                                              \
    float4v c0 = *(const float4v*)(&wo[j][kk_]);                             \
    float4v c1 = *(const float4v*)(&wo[j][(kk_) + 4]);                       \
    acc[j] = fmaf(c0[0], wv_[0], acc[j]);                                    \
    acc[j] = fmaf(c0[1], wv_[1], acc[j]);                                    \
    acc[j] = fmaf(c0[2], wv_[2], acc[j]);                                    \
    acc[j] = fmaf(c0[3], wv_[3], acc[j]);                                    \
    acc[j] = fmaf(c1[0], wv_[4], acc[j]);                                    \
    acc[j] = fmaf(c1[1], wv_[5], acc[j]);                                    \
    acc[j] = fmaf(c1[2], wv_[6], acc[j]);                                    \
    acc[j] = fmaf(c1[3], wv_[7], acc[j]);                                    \
  }

  for (int k = 0; k < 240; k += 16) {
#pragma unroll
    for (int u = 0; u < 8; ++u) wvB[u] = Wv[(size_t)(k + 8 + u) * 768 + h];
    PFMA(wvA, k)
#pragma unroll
    for (int u = 0; u < 8; ++u) wvA[u] = Wv[(size_t)(k + 16 + u) * 768 + h];
    PFMA(wvB, k + 8)
  }
#pragma unroll
  for (int u = 0; u < 8; ++u) wvB[u] = Wv[(size_t)(248 + u) * 768 + h];
  PFMA(wvA, 240)
  PFMA(wvB, 248)
#undef PFMA

  const int kt = h >> 5, qq = (h >> 3) & 3, e = h & 7;
#pragma unroll
  for (int j = 0; j < 4; ++j)
    wt[(size_t)kt * 24576 + (o0 + j) * 32 + qq * 8 + e] = f16b(acc[j]);
}

// ---------------- main: out[16384,768] = x @ W^T, 16 waves/block ----------
// Block: 1024 thr / 16 waves; 64 rows x 768 cols; wave w owns cols
// w*48..+47 (disjoint -> W read once per block). LDS: x stripe f16
// [64][96 chunks], chunk stored at c^(row&7). 96 KB -> 1 block/CU,
// 16 waves/CU = 4 waves/SIMD (2x the latency hiding of r12-r19).
__global__ __launch_bounds__(1024, 4)   // forces VGPR <= 128
void gemm_xw(const float* __restrict__ x, const u16* __restrict__ wt,
             float* __restrict__ out) {
  __shared__ __align__(16) u16 S[64 * 768];       // 96 KB

  const int tid = threadIdx.x;
  const int w = tid >> 6, l = tid & 63;
  const int q = l >> 4, mr = l & 15;
  const int row0 = blockIdx.x * 64;

  // B-frag lane base: wt + col*32 + q*8, col = w*48 + jn*16 + mr
  const u16* wl = wt + (w * 48 + mr) * 32 + q * 8;
  const int akey = mr & 7;

  // ---- stage x[64][768] fp32 -> LDS f16, chunk-swizzled ----
  // 1024 thr: 16 thr/row, 6 chunks each (half the per-thread work of r12).
  {
    const int sr = tid >> 4, m = tid & 15;        // row 0..63
    const float* gr = x + (size_t)(row0 + sr) * 768;
    u16* lr = S + sr * 768;
    const int key = sr & 7;
#pragma unroll
    for (int j = 0; j < 6; ++j) {
      const int c = m + 16 * j;                   // chunk 0..95
      float4v v0 = *(const float4v*)(gr + c * 8);
      float4v v1 = *(const float4v*)(gr + c * 8 + 4);
      union { u16 h[8]; short8 s; } p;
#pragma unroll
      for (int e = 0; e < 4; ++e) { p.h[e] = f16b(v0[e]); p.h[e + 4] = f16b(v1[e]); }
      *(short8*)(lr + ((c ^ key) << 3)) = p.s;
    }
  }
  __syncthreads();                                // the ONLY barrier

  float4v acc[4][3];
#pragma unroll
  for (int i = 0; i < 4; ++i)
#pragma unroll
    for (int j = 0; j < 3; ++j) acc[i][j] = (float4v){0.f, 0.f, 0.f, 0.f};

  f16x8 a0[4], a1[4], b0[3], b1[3];

#define LDA(av_, kt_)                                                        \
  _Pragma("unroll")                                                          \
  for (int im = 0; im < 4; ++im)                                             \
    av_[im] = *(const f16x8*)(                                               \
        &S[(im * 16 + mr) * 768 + ((((kt_) * 4 + q) ^ akey) << 3)]);

#define LDB(bv_, kt_)                                                        \
  { const u16* gp = wl + (size_t)(kt_) * 24576;                              \
    _Pragma("unroll")                                                        \
    for (int jn = 0; jn < 3; ++jn)                                           \
      bv_[jn] = *(const f16x8*)(gp + jn * 512); }

#define MM(av_, bv_)                                                         \
  { __builtin_amdgcn_s_setprio(1);                                           \
    _Pragma("unroll")                                                        \
    for (int im = 0; im < 4; ++im)                                           \
      _Pragma("unroll")                                                      \
      for (int jn = 0; jn < 3; ++jn)                                         \
        acc[im][jn] = __builtin_amdgcn_mfma_f32_16x16x32_f16(                \
            av_[im], bv_[jn], acc[im][jn], 0, 0, 0);                         \
    __builtin_amdgcn_s_setprio(0); }

  LDB(b0, 0)
  LDA(a0, 0)
  for (int kt = 0; kt < 22; kt += 2) {
    LDB(b1, kt + 1)
    LDA(a1, kt + 1)
    MM(a0, b0)
    LDB(b0, kt + 2)
    LDA(a0, kt + 2)
    MM(a1, b1)
  }
  LDB(b1, 23)
  LDA(a1, 23)
  MM(a0, b0)
  MM(a1, b1)

#undef LDA
#undef LDB
#undef MM

  // ---- epilogue: C/D col=lane&15, row=q*4+reg (m89-verified) ----
#pragma unroll
  for (int im = 0; im < 4; ++im)
#pragma unroll
    for (int jn = 0; jn < 3; ++jn) {
      const int r0 = row0 + im * 16 + q * 4;
      const int c  = w * 48 + jn * 16 + mr;
#pragma unroll
      for (int r = 0; r < 4; ++r)
        out[(size_t)(r0 + r) * 768 + c] = acc[im][jn][r];
    }
}

// ---------------- fallback (no workspace): verified r7 kernel ----------------
__global__ __launch_bounds__(512, 1)
void fused_fallback(const float* __restrict__ x,
                    const float* __restrict__ Wv, const float* __restrict__ Wo,
                    float* __restrict__ out) {
  __shared__ __align__(16) u16 As[64 * 32];
  __shared__ __align__(16) u16 Bs[256 * 32];
  __shared__ __align__(16) u16 Vs[64 * 264];

  const int tid = threadIdx.x;
  const int w  = tid >> 6, l = tid & 63;
  const int q  = l >> 4, mr = l & 15;
  const int wm = w & 1, wn = w >> 1;
  const int row0 = blockIdx.x * 64;
  const int xr = tid >> 3, xg = (tid & 7) * 4;
  const int wr = tid >> 1, wh = (tid & 1) * 16;

  float4v acc[2][4];
#pragma unroll
  for (int i = 0; i < 2; ++i)
#pragma unroll
    for (int j = 0; j < 4; ++j) acc[i][j] = (float4v){0.f, 0.f, 0.f, 0.f};

  for (int kt = 0; kt < 24; ++kt) {
    const int k0 = kt * 32;
    {
      float4v v = *(const float4v*)(x + (size_t)(row0 + xr) * 768 + k0 + xg);
      union { u16 h[4]; uint2 u; } p;
      p.h[0] = f32_to_bf16(v[0]); p.h[1] = f32_to_bf16(v[1]);
      p.h[2] = f32_to_bf16(v[2]); p.h[3] = f32_to_bf16(v[3]);
      *(uint2*)(As + xr * 32 + xg) = p.u;
    }
    {
      const float* g = Wv + (size_t)wr * 768 + k0 + wh;
      union { u16 h[16]; short8 s[2]; } p;
#pragma unroll
      for (int u = 0; u < 4; ++u) {
        float4v v = *(const float4v*)(g + u * 4);
        p.h[u * 4 + 0] = f32_to_bf16(v[0]); p.h[u * 4 + 1] = f32_to_bf16(v[1]);
        p.h[u * 4 + 2] = f32_to_bf16(v[2]); p.h[u * 4 + 3] = f32_to_bf16(v[3]);
      }
      *(short8*)(Bs + wr * 32 + wh) = p.s[0];
      *(short8*)(Bs + wr * 32 + wh + 8) = p.s[1];
    }
    __syncthreads();

    short8 a[2], b[4];
#pragma unroll
    for (int i = 0; i < 2; ++i)
      a[i] = *(const short8*)(As + (wm * 32 + i * 16 + mr) * 32 + q * 8);
#pragma unroll
    for (int j = 0; j < 4; ++j)
      b[j] = *(const short8*)(Bs + (wn * 64 + j * 16 + mr) * 32 + q * 8);
#pragma unroll
    for (int i = 0; i < 2; ++i)
#pragma unroll
      for (int j = 0; j < 4; ++j)
        acc[i][j] = __builtin_amdgcn_mfma_f32_16x16x32_bf16(a[i], b[j], acc[i][j], 0, 0, 0);
    __syncthreads();
  }

#pragma unroll
  for (int i = 0; i < 2; ++i)
#pragma unroll
    for (int j = 0; j < 4; ++j) {
      int row = wm * 32 + i * 16 + q * 4;
      int col = wn * 64 + j * 16 + mr;
#pragma unroll
      for (int r = 0; r < 4; ++r)
        Vs[(row + r) * 264 + col] = f32_to_bf16(acc[i][j][r]);
    }
  __syncthreads();

  for (int c = 0; c < 3; ++c) {
    float4v acc2[2][4];
#pragma unroll
    for (int i = 0; i < 2; ++i)
#pragma unroll
      for (int j = 0; j < 4; ++j) acc2[i][j] = (float4v){0.f, 0.f, 0.f, 0.f};

    for (int kt = 0; kt < 8; ++kt) {
      const int k0 = kt * 32;
      {
        const float* g = Wo + (size_t)(c * 256 + wr) * 256 + k0 + wh;
        union { u16 h[16]; short8 s[2]; } p;
#pragma unroll
        for (int u = 0; u < 4; ++u) {
          float4v v = *(const float4v*)(g + u * 4);
          p.h[u * 4 + 0] = f32_to_bf16(v[0]); p.h[u * 4 + 1] = f32_to_bf16(v[1]);
          p.h[u * 4 + 2] = f32_to_bf16(v[2]); p.h[u * 4 + 3] = f32_to_bf16(v[3]);
        }
        *(short8*)(Bs + wr * 32 + wh) = p.s[0];
        *(short8*)(Bs + wr * 32 + wh + 8) = p.s[1];
      }
      __syncthreads();

      short8 a[2], b[4];
#pragma unroll
      for (int i = 0; i < 2; ++i)
        a[i] = *(const short8*)(Vs + (wm * 32 + i * 16 + mr) * 264 + k0 + q * 8);
#pragma unroll
      for (int j = 0; j < 4; ++j)
        b[j] = *(const short8*)(Bs + (wn * 64 + j * 16 + mr) * 32 + q * 8);
#pragma unroll
      for (int i = 0; i < 2; ++i)
#pragma unroll
        for (int j = 0; j < 4; ++j)
          acc2[i][j] = __builtin_amdgcn_mfma_f32_16x16x32_bf16(a[i], b[j], acc2[i][j], 0, 0, 0);
      __syncthreads();
    }

#pragma unroll
    for (int i = 0; i < 2; ++i)
#pragma unroll
      for (int j = 0; j < 4; ++j) {
        int row = row0 + wm * 32 + i * 16 + q * 4;
        int col = c * 256 + wn * 64 + j * 16 + mr;
#pragma unroll
        for (int r = 0; r < 4; ++r)
          out[(size_t)(row + r) * 768 + col] = acc2[i][j][r];
      }
  }
}

extern "C" void kernel_launch(void* const* d_in, const int* in_sizes, int n_in,
                              void* d_out, int out_size, void* d_ws, size_t ws_size,
                              hipStream_t stream) {
  (void)in_sizes; (void)n_in; (void)out_size;
  const float* x  = (const float*)d_in[0];  // [16384, 768]
  const float* Wv = (const float*)d_in[3];  // [256, 768]
  const float* Wo = (const float*)d_in[4];  // [768, 256]
  float* out = (float*)d_out;

  if (ws_size >= (size_t)768 * 768 * 2) {   // 1.18 MB f16 combined weight
    u16* wt = (u16*)d_ws;
    prep_w<<<dim3(576), dim3(256), 0, stream>>>(Wv, Wo, wt);
    gemm_xw<<<dim3(256), dim3(1024), 0, stream>>>(x, wt, out);
  } else {
    fused_fallback<<<dim3(256), dim3(512), 0, stream>>>(x, Wv, Wo, out);
  }
}